// Round 7
// baseline (764.122 us; speedup 1.0000x reference)
//
#include <hip/hip_runtime.h>

// ---------------------------------------------------------------------------
// GCNDecoder: 2x GCNConv(64->64, sym-norm, self-loops) + ReLU, readout MLP
// 64->64(relu)->384. Outputs (r[N,384], h[N,64]) concatenated in d_out.
//
// R2: bucket/CSR edge grouping (1 atomic/edge), wave-per-node aggregate.
// R3: fused readout; LDS-broadcast GEMM2 was LDS-pipe-bound (172us).
// R4-R8: zero-LDS readout via v_readlane. The m[16]+acc[96] live set
// (>64 regs) gets PARKED in AGPRs by the RA no matter what
// (launch_bounds, waves_per_eu, group-split all failed: 124/121/139us,
// VGPR_Count 48-76, occupancy 25-37%). Lesson: don't build structures
// whose live set exceeds the 64-reg bucket; the allocator wins.
//
// R9: two-kernel readout, both with the PROVEN transform shape (acc[16],
// ~30 live regs, no parking possible):
//   1. transform<true,true>: mid = relu(h@A1+b1) -> h2b   (~23us in R0)
//   2. readout2: mid @ A2 + b2, ONE block = 64 rows, 6 col-tiles looped
//      INSIDE the block. A-rows (16KB) stay L1-resident across tiles ->
//      the 6x re-read that cost R0 125MB of HBM FETCH now hits L1.
//      W per-lane from global (16KB/tile, L1/L2-hot), A via wave-uniform
//      float4 VMEM broadcast. No LDS, no syncthreads, no readlane.
// ---------------------------------------------------------------------------

typedef unsigned long long ull;

// ============================ shared kernels ================================

// Gather aggregation + ReLU. One wave per node, lane = feature (64 feats).
// BUCKET: base = node*64, count = meta[node].
// CSR:    base = meta[node], count = meta[node+1]-base.
// 4 independent accumulators = 4 outstanding gathers (latency-bound).
template <bool BUCKET>
__global__ void aggregate_kernel(const float* __restrict__ hin, float* __restrict__ hout,
                                 const int* __restrict__ meta,
                                 const int2* __restrict__ ent,
                                 const float* __restrict__ dinv, int n) {
    int gid = blockIdx.x * blockDim.x + threadIdx.x;
    int node = __builtin_amdgcn_readfirstlane(gid >> 6);   // wave-uniform -> SGPR
    int lane = threadIdx.x & 63;
    if (node >= n) return;
    float di = dinv[node];
    float acc0 = hin[(size_t)node * 64 + lane] * (di * di);  // self-loop (ew=1)
    float acc1 = 0.0f, acc2 = 0.0f, acc3 = 0.0f;
    int b, c;
    if (BUCKET) { b = node << 6; c = meta[node]; if (c > 64) c = 64; }
    else        { b = meta[node]; c = meta[node + 1] - b; }
    int e = b, end = b + c;
    for (; e + 4 <= end; e += 4) {
        int2 p0 = ent[e];       // wave-uniform scalar 8B loads
        int2 p1 = ent[e + 1];
        int2 p2 = ent[e + 2];
        int2 p3 = ent[e + 3];
        acc0 = fmaf(__int_as_float(p0.y), hin[(size_t)p0.x * 64 + lane], acc0);
        acc1 = fmaf(__int_as_float(p1.y), hin[(size_t)p1.x * 64 + lane], acc1);
        acc2 = fmaf(__int_as_float(p2.y), hin[(size_t)p2.x * 64 + lane], acc2);
        acc3 = fmaf(__int_as_float(p3.y), hin[(size_t)p3.x * 64 + lane], acc3);
    }
    for (; e < end; ++e) {
        int2 p0 = ent[e];
        acc0 = fmaf(__int_as_float(p0.y), hin[(size_t)p0.x * 64 + lane], acc0);
    }
    hout[(size_t)node * 64 + lane] = fmaxf((acc0 + acc1) + (acc2 + acc3), 0.0f);
}

// out[r, coff+c] = sum_k A[r,k] * W[k, coff+c] (+bias) (+relu)
// Block: 256 threads = 4 waves x 16 rows. W 64x64 tile in LDS.
template <bool BIAS, bool RELU>
__global__ void transform_kernel(const float* __restrict__ A, const float* __restrict__ W,
                                 const float* __restrict__ bias, float* __restrict__ out,
                                 int n, int ldw, int ldo) {
    __shared__ float Wl[64 * 64];
    int t = threadIdx.x;
    int coff = blockIdx.y * 64;
    for (int i = t; i < 4096; i += 256) {
        int k = i >> 6, c = i & 63;
        Wl[i] = W[k * ldw + coff + c];
    }
    __syncthreads();
    int wv = t >> 6, lane = t & 63;
    int row0 = (blockIdx.x * 4 + wv) * 16;
    row0 = __builtin_amdgcn_readfirstlane(row0);
    if (row0 >= n) return;
    float bv = BIAS ? bias[coff + lane] : 0.0f;
    float acc[16];
#pragma unroll
    for (int i = 0; i < 16; i++) acc[i] = bv;
    const float* Ar = A + (size_t)row0 * 64;
    int nrows = n - row0;
    if (nrows > 16) nrows = 16;
    if (nrows == 16) {
        for (int k0 = 0; k0 < 64; k0 += 4) {
            float w0 = Wl[(k0 + 0) * 64 + lane];
            float w1 = Wl[(k0 + 1) * 64 + lane];
            float w2 = Wl[(k0 + 2) * 64 + lane];
            float w3 = Wl[(k0 + 3) * 64 + lane];
#pragma unroll
            for (int i = 0; i < 16; i++) {
                float4 a = *(const float4*)(Ar + i * 64 + k0);
                acc[i] = fmaf(a.x, w0, fmaf(a.y, w1, fmaf(a.z, w2, fmaf(a.w, w3, acc[i]))));
            }
        }
#pragma unroll
        for (int i = 0; i < 16; i++) {
            float v = acc[i];
            if (RELU) v = fmaxf(v, 0.0f);
            out[(size_t)(row0 + i) * ldo + coff + lane] = v;
        }
    } else {
        for (int k = 0; k < 64; k++) {
            float w = Wl[k * 64 + lane];
            for (int i = 0; i < nrows; i++) acc[i] = fmaf(Ar[i * 64 + k], w, acc[i]);
        }
        for (int i = 0; i < nrows; i++) {
            float v = acc[i];
            if (RELU) v = fmaxf(v, 0.0f);
            out[(size_t)(row0 + i) * ldo + coff + lane] = v;
        }
    }
}

// Readout GEMM2: r = mid @ A2 + b2. Wave owns 16 rows; block owns 64 rows
// and loops all 6 column-tiles so the A-rows (64x256B = 16KB) stay
// L1-resident across tiles (kills R0's 6x HBM refetch). W read per-lane
// from global (16KB/tile working set, L1/L2-hot). A read as wave-uniform
// float4 VMEM broadcast (VMEM pipe -- NOT the LDS pipe, R3's mistake).
// True live set ~30 regs: nothing for the RA to park (R4-R8's mistake).
__global__ void __launch_bounds__(256)
readout2_kernel(const float* __restrict__ M, const float* __restrict__ A2,
                const float* __restrict__ b2, float* __restrict__ out, int n) {
    int t = threadIdx.x;
    int wv = t >> 6, lane = t & 63;
    int wrow = __builtin_amdgcn_readfirstlane(blockIdx.x * 64 + wv * 16);
    if (wrow >= n) return;
    int nrows = n - wrow;
    if (nrows > 16) nrows = 16;
    const float* Ar = M + (size_t)wrow * 64;

#pragma unroll 1
    for (int tt = 0; tt < 6; tt++) {
        const float* Wp = A2 + tt * 64 + lane;
        float bv = b2[tt * 64 + lane];
        float acc[16];
#pragma unroll
        for (int i = 0; i < 16; i++) acc[i] = bv;
        if (nrows == 16) {
            for (int k0 = 0; k0 < 64; k0 += 4) {
                float w0 = Wp[(k0 + 0) * 384];     // per-lane coalesced, L1-hot
                float w1 = Wp[(k0 + 1) * 384];
                float w2 = Wp[(k0 + 2) * 384];
                float w3 = Wp[(k0 + 3) * 384];
#pragma unroll
                for (int i = 0; i < 16; i++) {
                    float4 a = *(const float4*)(Ar + i * 64 + k0);   // uniform VMEM broadcast
                    acc[i] = fmaf(a.x, w0, fmaf(a.y, w1, fmaf(a.z, w2, fmaf(a.w, w3, acc[i]))));
                }
            }
#pragma unroll
            for (int i = 0; i < 16; i++)
                out[(size_t)(wrow + i) * 384 + tt * 64 + lane] = acc[i];
        } else {
            for (int k = 0; k < 64; k++) {
                float w = Wp[k * 384];
                for (int i = 0; i < nrows; i++) acc[i] = fmaf(Ar[i * 64 + k], w, acc[i]);
            }
            for (int i = 0; i < nrows; i++)
                out[(size_t)(wrow + i) * 384 + tt * 64 + lane] = acc[i];
        }
    }
}

// ============================ bucket path ===================================

__global__ void init_cnt(int* cnt, int n) {
    int i = blockIdx.x * 256 + threadIdx.x;
    if (i < n) cnt[i] = 0;
}

// One atomic per edge: claim a slot in the target's bucket, store (src, ew).
__global__ void bfill_kernel(const int* __restrict__ row, const int* __restrict__ col,
                             const float* __restrict__ ew, int* cnt, int2* __restrict__ bucket,
                             int E) {
    int e = blockIdx.x * 256 + threadIdx.x;
    if (e < E) {
        int t = col[e];
        int p = atomicAdd(&cnt[t], 1);
        if (p < 64) bucket[((size_t)t << 6) + p] = make_int2(row[e], __float_as_int(ew[e]));
    }
}

// Wave per node: shuffle-reduce bucket weights -> dinv = rsqrt(1 + sum(ew)).
__global__ void bdinv_kernel(const int* __restrict__ cnt, const int2* __restrict__ bucket,
                             float* __restrict__ dinv, int n) {
    int gid = blockIdx.x * blockDim.x + threadIdx.x;
    int node = gid >> 6;
    int lane = threadIdx.x & 63;
    if (node >= n) return;
    int c = cnt[node]; if (c > 64) c = 64;
    float w = (lane < c) ? __int_as_float(bucket[((size_t)node << 6) + lane].y) : 0.0f;
    for (int m = 32; m; m >>= 1) w += __shfl_xor(w, m, 64);
    if (lane == 0) dinv[node] = rsqrtf(1.0f + w);
}

// Slot-parallel: overwrite stored ew with dinv[s]*ew*dinv[t].
__global__ void bnorm_kernel(const int* __restrict__ cnt, int2* bucket,
                             const float* __restrict__ dinv, int n) {
    int gid = blockIdx.x * blockDim.x + threadIdx.x;
    int node = gid >> 6;
    int slot = threadIdx.x & 63;
    if (node >= n) return;
    int c = cnt[node]; if (c > 64) c = 64;
    if (slot < c) {
        size_t idx = ((size_t)node << 6) + slot;
        int2 p = bucket[idx];
        float w = dinv[p.x] * __int_as_float(p.y) * dinv[node];
        bucket[idx].y = __float_as_int(w);
    }
}

// ============================ CSR fallback path =============================

__global__ void init_dc(ull* dc, int n) {
    int i = blockIdx.x * 256 + threadIdx.x;
    if (i < n) dc[i] = 0ull;
}

// Packed histogram: one u64 atomic per edge. hi32 = count, lo32 = deg*2^20.
__global__ void hist_packed(const int* __restrict__ col, const float* __restrict__ ew,
                            ull* dc, int E) {
    int e = blockIdx.x * 256 + threadIdx.x;
    if (e < E) {
        int t = col[e];
        ull v = (1ull << 32) | (unsigned)lrintf(ew[e] * 1048576.0f);
        atomicAdd(&dc[t], v);
    }
}

__global__ void unpack_kernel(const ull* __restrict__ dc, int* __restrict__ cnt,
                              float* __restrict__ dinv, int n) {
    int i = blockIdx.x * 256 + threadIdx.x;
    if (i < n) {
        ull v = dc[i];
        cnt[i] = (int)(v >> 32);
        dinv[i] = rsqrtf(1.0f + (float)(unsigned)v * (1.0f / 1048576.0f));
    }
}

// Block scan: each block scans 1024 counts (4/thread). Requires n % 4 == 0.
__global__ void scan1(const int* __restrict__ cnt, int* __restrict__ excl,
                      int* __restrict__ bsum, int n) {
    __shared__ int lds[256];
    int t = threadIdx.x;
    int idx = blockIdx.x * 1024 + t * 4;
    int4 c = make_int4(0, 0, 0, 0);
    if (idx < n) c = *(const int4*)(cnt + idx);
    int s = c.x + c.y + c.z + c.w;
    lds[t] = s;
    __syncthreads();
    for (int off = 1; off < 256; off <<= 1) {
        int u = (t >= off) ? lds[t - off] : 0;
        __syncthreads();
        lds[t] += u;
        __syncthreads();
    }
    int incl = lds[t];
    if (t == 255) bsum[blockIdx.x] = incl;
    int e0 = incl - s;
    if (idx < n) {
        excl[idx + 0] = e0;
        excl[idx + 1] = e0 + c.x;
        excl[idx + 2] = e0 + c.x + c.y;
        excl[idx + 3] = e0 + c.x + c.y + c.z;
    }
}

__global__ void scan2(int* bsum, int nb) {
    __shared__ int lds[256];
    int t = threadIdx.x;
    int v = (t < nb) ? bsum[t] : 0;
    lds[t] = v;
    __syncthreads();
    for (int off = 1; off < 256; off <<= 1) {
        int u = (t >= off) ? lds[t - off] : 0;
        __syncthreads();
        lds[t] += u;
        __syncthreads();
    }
    if (t < nb) bsum[t] = lds[t] - v;
}

__global__ void scan3(int* __restrict__ ptr, const int* __restrict__ bsum,
                      int* __restrict__ pfill, int n, int E) {
    int i = blockIdx.x * 256 + threadIdx.x;
    if (i < n) {
        int v = ptr[i] + bsum[i >> 10];
        ptr[i] = v;
        pfill[i] = v;
    }
    if (i == n) ptr[n] = E;
}

// Scatter each edge into its CSR slot, storing (src, norm) interleaved.
__global__ void fill_kernel(const int* __restrict__ row, const int* __restrict__ col,
                            const float* __restrict__ ew, const float* __restrict__ dinv,
                            int* pfill, int2* __restrict__ ent, int E) {
    int e = blockIdx.x * 256 + threadIdx.x;
    if (e < E) {
        int t = col[e], s = row[e];
        int p = atomicAdd(&pfill[t], 1);
        ent[p] = make_int2(s, __float_as_int(dinv[s] * ew[e] * dinv[t]));
    }
}

// ============================ launch ========================================

extern "C" void kernel_launch(void* const* d_in, const int* in_sizes, int n_in,
                              void* d_out, int out_size, void* d_ws, size_t ws_size,
                              hipStream_t stream) {
    const float* x  = (const float*)d_in[0];
    const int*   ei = (const int*)d_in[1];
    const float* ew = (const float*)d_in[2];
    const float* W1 = (const float*)d_in[3];
    const float* W2 = (const float*)d_in[4];
    const float* A1 = (const float*)d_in[5];
    const float* b1 = (const float*)d_in[6];
    const float* A2 = (const float*)d_in[7];
    const float* b2 = (const float*)d_in[8];
    float* out = (float*)d_out;

    const int N = in_sizes[0] / 64;
    const int E = in_sizes[2];
    const int* row = ei;
    const int* col = ei + E;

    float* r_out = out;                       // [N, 384]
    float* h_out = out + (size_t)N * 384;     // [N, 64]

    dim3 tgrid((N + 63) / 64, 1);
    int rblocks = (N + 63) / 64;
    int aggblocks = (int)(((size_t)N * 64 + 255) / 256);
    int nblk = (N + 255) / 256;
    int eblk = (E + 255) / 256;

    char* p = (char*)d_ws;
    auto alloc = [&](size_t bytes) { void* r = (void*)p; p += (bytes + 255) & ~(size_t)255; return r; };

    // Bucket path needs: cnt + dinv + bucket(N*64*8) + h1 + h2b
    size_t need_bucket = 256 * 8 + (size_t)N * 4 * 2 + ((size_t)N << 6) * 8 + (size_t)N * 64 * 4 * 2
                       + 64 * 1024;  // slack for 256B rounding
    if (ws_size >= need_bucket) {
        // ---------------- bucket path: 1 atomic pass total ----------------
        int*   cnt    = (int*)alloc((size_t)N * 4);
        float* dinv   = (float*)alloc((size_t)N * 4);
        int2*  bucket = (int2*)alloc(((size_t)N << 6) * 8);
        float* h1     = (float*)alloc((size_t)N * 64 * 4);
        float* h2b    = (float*)alloc((size_t)N * 64 * 4);

        init_cnt<<<nblk, 256, 0, stream>>>(cnt, N);
        bfill_kernel<<<eblk, 256, 0, stream>>>(row, col, ew, cnt, bucket, E);
        bdinv_kernel<<<aggblocks, 256, 0, stream>>>(cnt, bucket, dinv, N);
        bnorm_kernel<<<aggblocks, 256, 0, stream>>>(cnt, bucket, dinv, N);

        transform_kernel<false, false><<<tgrid, 256, 0, stream>>>(x, W1, nullptr, h1, N, 64, 64);
        aggregate_kernel<true><<<aggblocks, 256, 0, stream>>>(h1, h2b, cnt, bucket, dinv, N);
        transform_kernel<false, false><<<tgrid, 256, 0, stream>>>(h2b, W2, nullptr, h1, N, 64, 64);
        aggregate_kernel<true><<<aggblocks, 256, 0, stream>>>(h1, h_out, cnt, bucket, dinv, N);
        transform_kernel<true, true><<<tgrid, 256, 0, stream>>>(h_out, A1, b1, h2b, N, 64, 64);
        readout2_kernel<<<rblocks, 256, 0, stream>>>(h2b, A2, b2, r_out, N);
    } else {
        // ---------------- CSR fallback: packed hist + scan + fill ---------
        ull*   dc   = (ull*)alloc((size_t)N * 8);
        int*   cnt  = (int*)alloc((size_t)N * 4);        // becomes pfill in place
        float* dinv = (float*)alloc((size_t)N * 4);
        int*   ptr  = (int*)alloc((size_t)(N + 1) * 4);
        int*   bsum = (int*)alloc(1024);
        int2*  ent  = (int2*)alloc((size_t)E * 8);
        float* h1   = (float*)alloc((size_t)N * 64 * 4);
        float* h2b  = (float*)alloc((size_t)N * 64 * 4);
        int*   pfill = cnt;
        int nb = (N + 1023) / 1024;

        init_dc<<<nblk, 256, 0, stream>>>(dc, N);
        hist_packed<<<eblk, 256, 0, stream>>>(col, ew, dc, E);
        unpack_kernel<<<nblk, 256, 0, stream>>>(dc, cnt, dinv, N);
        scan1<<<nb, 256, 0, stream>>>(cnt, ptr, bsum, N);
        scan2<<<1, 256, 0, stream>>>(bsum, nb);
        scan3<<<(N + 256) / 256, 256, 0, stream>>>(ptr, bsum, pfill, N, E);
        fill_kernel<<<eblk, 256, 0, stream>>>(row, col, ew, dinv, pfill, ent, E);

        transform_kernel<false, false><<<tgrid, 256, 0, stream>>>(x, W1, nullptr, h1, N, 64, 64);
        aggregate_kernel<false><<<aggblocks, 256, 0, stream>>>(h1, h2b, ptr, ent, dinv, N);
        transform_kernel<false, false><<<tgrid, 256, 0, stream>>>(h2b, W2, nullptr, h1, N, 64, 64);
        aggregate_kernel<false><<<aggblocks, 256, 0, stream>>>(h1, h_out, ptr, ent, dinv, N);
        transform_kernel<true, true><<<tgrid, 256, 0, stream>>>(h_out, A1, b1, h2b, N, 64, 64);
        readout2_kernel<<<rblocks, 256, 0, stream>>>(h2b, A2, b2, r_out, N);
    }
}

// Round 8
// 642.941 us; speedup vs baseline: 1.1885x; 1.1885x over previous
//
#include <hip/hip_runtime.h>

// ---------------------------------------------------------------------------
// GCNDecoder: 2x GCNConv(64->64, sym-norm, self-loops) + ReLU, readout MLP
// 64->64(relu)->384. Outputs (r[N,384], h[N,64]) concatenated in d_out.
//
// R2: bucket/CSR edge grouping (1 atomic/edge), wave-per-node aggregate.
// R3: fused readout; LDS-broadcast GEMM2 was LDS-pipe-bound (172us).
// R4-R8: zero-LDS readlane readout, 16 rows/wave. Unified (VGPR+AGPR)
// demand ~130-176 caps occupancy at 2-3 waves/SIMD -> latency-bound
// (VALUBusy 35%, 121-139us). rocprof VGPR_Count excludes AGPRs; "parking"
// is an occupancy problem, not an accvgpr-move problem.
// R9: two-kernel readout w/ block-level tile loop: L1 can't hold 4 blocks
// x 16KB A -> mid refetched (FETCH 89MB), VMEM-latency-bound, 190us.
//
// R10: fused readlane readout with 4 ROWS/WAVE. Live set = m[4] +
// acc[6][4] + w[6] + temps ~= 44 regs total -> any VGPR/AGPR split stays
// under 64 -> 8 waves/SIMD, full latency hiding. ~2600 VALU instr/wave
// x 25k waves / 1024 SIMDs ~= 53us VALU floor; 180MB traffic ~= 28us
// memory floor (overlapped). No mid round-trip, no LDS, no L1 residency
// assumption (h streamed once, A1/A2 112KB cache-hot).
// ---------------------------------------------------------------------------

typedef unsigned long long ull;

// ============================ shared kernels ================================

// Gather aggregation + ReLU. One wave per node, lane = feature (64 feats).
// BUCKET: base = node*64, count = meta[node].
// CSR:    base = meta[node], count = meta[node+1]-base.
// 4 independent accumulators = 4 outstanding gathers (latency-bound).
template <bool BUCKET>
__global__ void aggregate_kernel(const float* __restrict__ hin, float* __restrict__ hout,
                                 const int* __restrict__ meta,
                                 const int2* __restrict__ ent,
                                 const float* __restrict__ dinv, int n) {
    int gid = blockIdx.x * blockDim.x + threadIdx.x;
    int node = __builtin_amdgcn_readfirstlane(gid >> 6);   // wave-uniform -> SGPR
    int lane = threadIdx.x & 63;
    if (node >= n) return;
    float di = dinv[node];
    float acc0 = hin[(size_t)node * 64 + lane] * (di * di);  // self-loop (ew=1)
    float acc1 = 0.0f, acc2 = 0.0f, acc3 = 0.0f;
    int b, c;
    if (BUCKET) { b = node << 6; c = meta[node]; if (c > 64) c = 64; }
    else        { b = meta[node]; c = meta[node + 1] - b; }
    int e = b, end = b + c;
    for (; e + 4 <= end; e += 4) {
        int2 p0 = ent[e];       // wave-uniform scalar 8B loads
        int2 p1 = ent[e + 1];
        int2 p2 = ent[e + 2];
        int2 p3 = ent[e + 3];
        acc0 = fmaf(__int_as_float(p0.y), hin[(size_t)p0.x * 64 + lane], acc0);
        acc1 = fmaf(__int_as_float(p1.y), hin[(size_t)p1.x * 64 + lane], acc1);
        acc2 = fmaf(__int_as_float(p2.y), hin[(size_t)p2.x * 64 + lane], acc2);
        acc3 = fmaf(__int_as_float(p3.y), hin[(size_t)p3.x * 64 + lane], acc3);
    }
    for (; e < end; ++e) {
        int2 p0 = ent[e];
        acc0 = fmaf(__int_as_float(p0.y), hin[(size_t)p0.x * 64 + lane], acc0);
    }
    hout[(size_t)node * 64 + lane] = fmaxf((acc0 + acc1) + (acc2 + acc3), 0.0f);
}

// out[r, coff+c] = sum_k A[r,k] * W[k, coff+c] (+bias) (+relu)
// Block: 256 threads = 4 waves x 16 rows. W 64x64 tile in LDS.
template <bool BIAS, bool RELU>
__global__ void transform_kernel(const float* __restrict__ A, const float* __restrict__ W,
                                 const float* __restrict__ bias, float* __restrict__ out,
                                 int n, int ldw, int ldo) {
    __shared__ float Wl[64 * 64];
    int t = threadIdx.x;
    int coff = blockIdx.y * 64;
    for (int i = t; i < 4096; i += 256) {
        int k = i >> 6, c = i & 63;
        Wl[i] = W[k * ldw + coff + c];
    }
    __syncthreads();
    int wv = t >> 6, lane = t & 63;
    int row0 = (blockIdx.x * 4 + wv) * 16;
    row0 = __builtin_amdgcn_readfirstlane(row0);
    if (row0 >= n) return;
    float bv = BIAS ? bias[coff + lane] : 0.0f;
    float acc[16];
#pragma unroll
    for (int i = 0; i < 16; i++) acc[i] = bv;
    const float* Ar = A + (size_t)row0 * 64;
    int nrows = n - row0;
    if (nrows > 16) nrows = 16;
    if (nrows == 16) {
        for (int k0 = 0; k0 < 64; k0 += 4) {
            float w0 = Wl[(k0 + 0) * 64 + lane];
            float w1 = Wl[(k0 + 1) * 64 + lane];
            float w2 = Wl[(k0 + 2) * 64 + lane];
            float w3 = Wl[(k0 + 3) * 64 + lane];
#pragma unroll
            for (int i = 0; i < 16; i++) {
                float4 a = *(const float4*)(Ar + i * 64 + k0);
                acc[i] = fmaf(a.x, w0, fmaf(a.y, w1, fmaf(a.z, w2, fmaf(a.w, w3, acc[i]))));
            }
        }
#pragma unroll
        for (int i = 0; i < 16; i++) {
            float v = acc[i];
            if (RELU) v = fmaxf(v, 0.0f);
            out[(size_t)(row0 + i) * ldo + coff + lane] = v;
        }
    } else {
        for (int k = 0; k < 64; k++) {
            float w = Wl[k * 64 + lane];
            for (int i = 0; i < nrows; i++) acc[i] = fmaf(Ar[i * 64 + k], w, acc[i]);
        }
        for (int i = 0; i < nrows; i++) {
            float v = acc[i];
            if (RELU) v = fmaxf(v, 0.0f);
            out[(size_t)(row0 + i) * ldo + coff + lane] = v;
        }
    }
}

// Fused readout, 4 rows/wave: r = relu(h @ A1 + b1) @ A2 + b2.
// GEMM1 leaves mid in regs lane=k layout (m[i] in lane k == mid[row i][k]);
// GEMM2 broadcasts via v_readlane. Live set m[4]+acc[6][4]+w[6]+temps ~44
// regs -> total (VGPR+AGPR however the RA splits) < 64 -> 8 waves/SIMD.
// (16 rows/wave needed ~130 unified regs -> 2-3 waves -> latency-bound,
// R4-R8. 4 rows trades +20% instr overhead for 3x the latency hiding.)
__global__ void __launch_bounds__(256)
readout_kernel(const float* __restrict__ H, const float* __restrict__ A1,
               const float* __restrict__ b1, const float* __restrict__ A2,
               const float* __restrict__ b2, float* __restrict__ out, int n) {
    int t = threadIdx.x;
    int wv = t >> 6, lane = t & 63;
    int wrow = __builtin_amdgcn_readfirstlane(blockIdx.x * 16 + wv * 4);
    if (wrow >= n) return;
    int nr = n - wrow;
    if (nr > 4) nr = 4;

    // Clamped row offsets: i >= nr reads row 0 (in-bounds, discarded later).
    int roff[4];
#pragma unroll
    for (int i = 0; i < 4; i++) roff[i] = (i < nr ? i : 0) * 64;

    // ---- GEMM1: m[i] = relu(sum_k H[wrow+i][k] * A1[k][lane] + b1[lane]) ----
    float m[4];
    float bv = b1[lane];
#pragma unroll
    for (int i = 0; i < 4; i++) m[i] = bv;
    const float* Ar = H + (size_t)wrow * 64;
    for (int k0 = 0; k0 < 64; k0 += 4) {
        float w0 = A1[(k0 + 0) * 64 + lane];    // per-lane, L1-hot (16KB)
        float w1 = A1[(k0 + 1) * 64 + lane];
        float w2 = A1[(k0 + 2) * 64 + lane];
        float w3 = A1[(k0 + 3) * 64 + lane];
#pragma unroll
        for (int i = 0; i < 4; i++) {
            float4 a = *(const float4*)(Ar + roff[i] + k0);   // wave-uniform -> s_load
            m[i] = fmaf(a.x, w0, fmaf(a.y, w1, fmaf(a.z, w2, fmaf(a.w, w3, m[i]))));
        }
    }
#pragma unroll
    for (int i = 0; i < 4; i++) m[i] = fmaxf(m[i], 0.0f);

    // ---- GEMM2: out[i][tt*64+lane] = sum_k readlane(m[i],k) * A2[k][tt*64+lane] ----
    float acc[6][4];
#pragma unroll
    for (int tt = 0; tt < 6; tt++) {
        float b = b2[tt * 64 + lane];
#pragma unroll
        for (int i = 0; i < 4; i++) acc[tt][i] = b;
    }
    const float* A2p = A2 + lane;
#pragma unroll 4
    for (int k = 0; k < 64; k++) {
        float w[6];
#pragma unroll
        for (int tt = 0; tt < 6; tt++) w[tt] = A2p[k * 384 + tt * 64];  // coalesced, L1/L2-hot
#pragma unroll
        for (int i = 0; i < 4; i++) {
            float s = __int_as_float(__builtin_amdgcn_readlane(__float_as_int(m[i]), k));
#pragma unroll
            for (int tt = 0; tt < 6; tt++) acc[tt][i] = fmaf(s, w[tt], acc[tt][i]);
        }
    }

    // Fully-unrolled store; uniform guard keeps indices compile-time.
#pragma unroll
    for (int i = 0; i < 4; i++) {
        if (i < nr) {
#pragma unroll
            for (int tt = 0; tt < 6; tt++)
                out[(size_t)(wrow + i) * 384 + tt * 64 + lane] = acc[tt][i];
        }
    }
}

// ============================ bucket path ===================================

__global__ void init_cnt(int* cnt, int n) {
    int i = blockIdx.x * 256 + threadIdx.x;
    if (i < n) cnt[i] = 0;
}

// One atomic per edge: claim a slot in the target's bucket, store (src, ew).
__global__ void bfill_kernel(const int* __restrict__ row, const int* __restrict__ col,
                             const float* __restrict__ ew, int* cnt, int2* __restrict__ bucket,
                             int E) {
    int e = blockIdx.x * 256 + threadIdx.x;
    if (e < E) {
        int t = col[e];
        int p = atomicAdd(&cnt[t], 1);
        if (p < 64) bucket[((size_t)t << 6) + p] = make_int2(row[e], __float_as_int(ew[e]));
    }
}

// Wave per node: shuffle-reduce bucket weights -> dinv = rsqrt(1 + sum(ew)).
__global__ void bdinv_kernel(const int* __restrict__ cnt, const int2* __restrict__ bucket,
                             float* __restrict__ dinv, int n) {
    int gid = blockIdx.x * blockDim.x + threadIdx.x;
    int node = gid >> 6;
    int lane = threadIdx.x & 63;
    if (node >= n) return;
    int c = cnt[node]; if (c > 64) c = 64;
    float w = (lane < c) ? __int_as_float(bucket[((size_t)node << 6) + lane].y) : 0.0f;
    for (int m = 32; m; m >>= 1) w += __shfl_xor(w, m, 64);
    if (lane == 0) dinv[node] = rsqrtf(1.0f + w);
}

// Slot-parallel: overwrite stored ew with dinv[s]*ew*dinv[t].
__global__ void bnorm_kernel(const int* __restrict__ cnt, int2* bucket,
                             const float* __restrict__ dinv, int n) {
    int gid = blockIdx.x * blockDim.x + threadIdx.x;
    int node = gid >> 6;
    int slot = threadIdx.x & 63;
    if (node >= n) return;
    int c = cnt[node]; if (c > 64) c = 64;
    if (slot < c) {
        size_t idx = ((size_t)node << 6) + slot;
        int2 p = bucket[idx];
        float w = dinv[p.x] * __int_as_float(p.y) * dinv[node];
        bucket[idx].y = __float_as_int(w);
    }
}

// ============================ CSR fallback path =============================

__global__ void init_dc(ull* dc, int n) {
    int i = blockIdx.x * 256 + threadIdx.x;
    if (i < n) dc[i] = 0ull;
}

// Packed histogram: one u64 atomic per edge. hi32 = count, lo32 = deg*2^20.
__global__ void hist_packed(const int* __restrict__ col, const float* __restrict__ ew,
                            ull* dc, int E) {
    int e = blockIdx.x * 256 + threadIdx.x;
    if (e < E) {
        int t = col[e];
        ull v = (1ull << 32) | (unsigned)lrintf(ew[e] * 1048576.0f);
        atomicAdd(&dc[t], v);
    }
}

__global__ void unpack_kernel(const ull* __restrict__ dc, int* __restrict__ cnt,
                              float* __restrict__ dinv, int n) {
    int i = blockIdx.x * 256 + threadIdx.x;
    if (i < n) {
        ull v = dc[i];
        cnt[i] = (int)(v >> 32);
        dinv[i] = rsqrtf(1.0f + (float)(unsigned)v * (1.0f / 1048576.0f));
    }
}

// Block scan: each block scans 1024 counts (4/thread). Requires n % 4 == 0.
__global__ void scan1(const int* __restrict__ cnt, int* __restrict__ excl,
                      int* __restrict__ bsum, int n) {
    __shared__ int lds[256];
    int t = threadIdx.x;
    int idx = blockIdx.x * 1024 + t * 4;
    int4 c = make_int4(0, 0, 0, 0);
    if (idx < n) c = *(const int4*)(cnt + idx);
    int s = c.x + c.y + c.z + c.w;
    lds[t] = s;
    __syncthreads();
    for (int off = 1; off < 256; off <<= 1) {
        int u = (t >= off) ? lds[t - off] : 0;
        __syncthreads();
        lds[t] += u;
        __syncthreads();
    }
    int incl = lds[t];
    if (t == 255) bsum[blockIdx.x] = incl;
    int e0 = incl - s;
    if (idx < n) {
        excl[idx + 0] = e0;
        excl[idx + 1] = e0 + c.x;
        excl[idx + 2] = e0 + c.x + c.y;
        excl[idx + 3] = e0 + c.x + c.y + c.z;
    }
}

__global__ void scan2(int* bsum, int nb) {
    __shared__ int lds[256];
    int t = threadIdx.x;
    int v = (t < nb) ? bsum[t] : 0;
    lds[t] = v;
    __syncthreads();
    for (int off = 1; off < 256; off <<= 1) {
        int u = (t >= off) ? lds[t - off] : 0;
        __syncthreads();
        lds[t] += u;
        __syncthreads();
    }
    if (t < nb) bsum[t] = lds[t] - v;
}

__global__ void scan3(int* __restrict__ ptr, const int* __restrict__ bsum,
                      int* __restrict__ pfill, int n, int E) {
    int i = blockIdx.x * 256 + threadIdx.x;
    if (i < n) {
        int v = ptr[i] + bsum[i >> 10];
        ptr[i] = v;
        pfill[i] = v;
    }
    if (i == n) ptr[n] = E;
}

// Scatter each edge into its CSR slot, storing (src, norm) interleaved.
__global__ void fill_kernel(const int* __restrict__ row, const int* __restrict__ col,
                            const float* __restrict__ ew, const float* __restrict__ dinv,
                            int* pfill, int2* __restrict__ ent, int E) {
    int e = blockIdx.x * 256 + threadIdx.x;
    if (e < E) {
        int t = col[e], s = row[e];
        int p = atomicAdd(&pfill[t], 1);
        ent[p] = make_int2(s, __float_as_int(dinv[s] * ew[e] * dinv[t]));
    }
}

// ============================ launch ========================================

extern "C" void kernel_launch(void* const* d_in, const int* in_sizes, int n_in,
                              void* d_out, int out_size, void* d_ws, size_t ws_size,
                              hipStream_t stream) {
    const float* x  = (const float*)d_in[0];
    const int*   ei = (const int*)d_in[1];
    const float* ew = (const float*)d_in[2];
    const float* W1 = (const float*)d_in[3];
    const float* W2 = (const float*)d_in[4];
    const float* A1 = (const float*)d_in[5];
    const float* b1 = (const float*)d_in[6];
    const float* A2 = (const float*)d_in[7];
    const float* b2 = (const float*)d_in[8];
    float* out = (float*)d_out;

    const int N = in_sizes[0] / 64;
    const int E = in_sizes[2];
    const int* row = ei;
    const int* col = ei + E;

    float* r_out = out;                       // [N, 384]
    float* h_out = out + (size_t)N * 384;     // [N, 64]

    dim3 tgrid((N + 63) / 64, 1);
    int rblocks = (N + 15) / 16;              // fused readout: 16 rows/block
    int aggblocks = (int)(((size_t)N * 64 + 255) / 256);
    int nblk = (N + 255) / 256;
    int eblk = (E + 255) / 256;

    char* p = (char*)d_ws;
    auto alloc = [&](size_t bytes) { void* r = (void*)p; p += (bytes + 255) & ~(size_t)255; return r; };

    // Bucket path needs: cnt + dinv + bucket(N*64*8) + h1 + h2b
    size_t need_bucket = 256 * 8 + (size_t)N * 4 * 2 + ((size_t)N << 6) * 8 + (size_t)N * 64 * 4 * 2
                       + 64 * 1024;  // slack for 256B rounding
    if (ws_size >= need_bucket) {
        // ---------------- bucket path: 1 atomic pass total ----------------
        int*   cnt    = (int*)alloc((size_t)N * 4);
        float* dinv   = (float*)alloc((size_t)N * 4);
        int2*  bucket = (int2*)alloc(((size_t)N << 6) * 8);
        float* h1     = (float*)alloc((size_t)N * 64 * 4);
        float* h2b    = (float*)alloc((size_t)N * 64 * 4);

        init_cnt<<<nblk, 256, 0, stream>>>(cnt, N);
        bfill_kernel<<<eblk, 256, 0, stream>>>(row, col, ew, cnt, bucket, E);
        bdinv_kernel<<<aggblocks, 256, 0, stream>>>(cnt, bucket, dinv, N);
        bnorm_kernel<<<aggblocks, 256, 0, stream>>>(cnt, bucket, dinv, N);

        transform_kernel<false, false><<<tgrid, 256, 0, stream>>>(x, W1, nullptr, h1, N, 64, 64);
        aggregate_kernel<true><<<aggblocks, 256, 0, stream>>>(h1, h2b, cnt, bucket, dinv, N);
        transform_kernel<false, false><<<tgrid, 256, 0, stream>>>(h2b, W2, nullptr, h1, N, 64, 64);
        aggregate_kernel<true><<<aggblocks, 256, 0, stream>>>(h1, h_out, cnt, bucket, dinv, N);
        readout_kernel<<<rblocks, 256, 0, stream>>>(h_out, A1, b1, A2, b2, r_out, N);
    } else {
        // ---------------- CSR fallback: packed hist + scan + fill ---------
        ull*   dc   = (ull*)alloc((size_t)N * 8);
        int*   cnt  = (int*)alloc((size_t)N * 4);        // becomes pfill in place
        float* dinv = (float*)alloc((size_t)N * 4);
        int*   ptr  = (int*)alloc((size_t)(N + 1) * 4);
        int*   bsum = (int*)alloc(1024);
        int2*  ent  = (int2*)alloc((size_t)E * 8);
        float* h1   = (float*)alloc((size_t)N * 64 * 4);
        float* h2b  = (float*)alloc((size_t)N * 64 * 4);
        int*   pfill = cnt;
        int nb = (N + 1023) / 1024;

        init_dc<<<nblk, 256, 0, stream>>>(dc, N);
        hist_packed<<<eblk, 256, 0, stream>>>(col, ew, dc, E);
        unpack_kernel<<<nblk, 256, 0, stream>>>(dc, cnt, dinv, N);
        scan1<<<nb, 256, 0, stream>>>(cnt, ptr, bsum, N);
        scan2<<<1, 256, 0, stream>>>(bsum, nb);
        scan3<<<(N + 256) / 256, 256, 0, stream>>>(ptr, bsum, pfill, N, E);
        fill_kernel<<<eblk, 256, 0, stream>>>(row, col, ew, dinv, pfill, ent, E);

        transform_kernel<false, false><<<tgrid, 256, 0, stream>>>(x, W1, nullptr, h1, N, 64, 64);
        aggregate_kernel<false><<<aggblocks, 256, 0, stream>>>(h1, h2b, ptr, ent, dinv, N);
        transform_kernel<false, false><<<tgrid, 256, 0, stream>>>(h2b, W2, nullptr, h1, N, 64, 64);
        aggregate_kernel<false><<<aggblocks, 256, 0, stream>>>(h1, h_out, ptr, ent, dinv, N);
        readout_kernel<<<rblocks, 256, 0, stream>>>(h_out, A1, b1, A2, b2, r_out, N);
        (void)h2b;
    }
}